// Round 4
// baseline (63.970 us; speedup 1.0000x reference)
//
#include <hip/hip_runtime.h>
#include <math.h>

#define NPTS 2048
#define THREADS 256

// ---------------- Fused kernel: reduction + per-batch 3x3 Kabsch ----------------
// Block b computes batch b's 16 weighted sums:
//   [0] w  [1..3] w*src  [4..6] w*tgt  [7..15] w*src_d*tgt_e (row-major)
// (w thresholded at 0.5, UNNORMALIZED), then thread 0 runs the fp64 Jacobi
// SVD / Kabsch epilogue and writes R (9) and t (3) directly. No second kernel.

// One transposed-butterfly level: halves the live accumulator count.
template <int M, int HALF>
__device__ inline void bflevel(float acc[16], int lane)
{
    const bool hi = lane & M;
#pragma unroll
    for (int j = 0; j < HALF; ++j) {
        const float keep = hi ? acc[j + HALF] : acc[j];
        const float send = hi ? acc[j] : acc[j + HALF];
        acc[j] = keep + __shfl_xor(send, M, 64);
    }
}

template <int P, int Q>
__device__ inline void jrot(double A[3][3], double V[3][3])
{
    const double apq = A[P][Q];
    if (fabs(apq) < 1e-300) return;
    const double theta = (A[Q][Q] - A[P][P]) / (2.0 * apq);
    const double t = ((theta >= 0.0) ? 1.0 : -1.0) /
                     (fabs(theta) + sqrt(theta * theta + 1.0));
    const double c = 1.0 / sqrt(t * t + 1.0);
    const double s = t * c;
#pragma unroll
    for (int k = 0; k < 3; ++k) {
        const double akp = A[k][P], akq = A[k][Q];
        A[k][P] = c * akp - s * akq;
        A[k][Q] = s * akp + c * akq;
    }
#pragma unroll
    for (int k = 0; k < 3; ++k) {
        const double apk = A[P][k], aqk = A[Q][k];
        A[P][k] = c * apk - s * aqk;
        A[Q][k] = s * apk + c * aqk;
    }
#pragma unroll
    for (int k = 0; k < 3; ++k) {
        const double vkp = V[k][P], vkq = V[k][Q];
        V[k][P] = c * vkp - s * vkq;
        V[k][Q] = s * vkp + c * vkq;
    }
}

__device__ inline void matvec3(const double H[3][3], const double v[3], double u[3])
{
#pragma unroll
    for (int i = 0; i < 3; ++i)
        u[i] = H[i][0] * v[0] + H[i][1] * v[1] + H[i][2] * v[2];
}

__device__ inline double dot3(const double a[3], const double b[3])
{
    return a[0] * b[0] + a[1] * b[1] + a[2] * b[2];
}

__device__ inline void cross3(const double a[3], const double b[3], double c[3])
{
    c[0] = a[1] * b[2] - a[2] * b[1];
    c[1] = a[2] * b[0] - a[0] * b[2];
    c[2] = a[0] * b[1] - a[1] * b[0];
}

__global__ __launch_bounds__(THREADS) void wp_fused_kernel(
    const float* __restrict__ src, const float* __restrict__ tgt,
    const float* __restrict__ w, float* __restrict__ out, int B)
{
    const int b = blockIdx.x;
    const int tid = threadIdx.x;
    const float* sp = src + (size_t)b * NPTS * 3;
    const float* tp = tgt + (size_t)b * NPTS * 3;
    const float* wp = w + (size_t)b * NPTS;

    float acc[16];
#pragma unroll
    for (int i = 0; i < 16; ++i) acc[i] = 0.f;

    // 2 iterations x 4 consecutive points per thread, all float4 loads.
#pragma unroll
    for (int it = 0; it < NPTS / (THREADS * 4); ++it) {
        const int n0 = it * (THREADS * 4) + tid * 4;
        const float4 wq = *reinterpret_cast<const float4*>(wp + n0);
        const float4* s4 = reinterpret_cast<const float4*>(sp + 3 * n0);
        const float4 sa = s4[0], sb = s4[1], sc = s4[2];
        const float4* t4 = reinterpret_cast<const float4*>(tp + 3 * n0);
        const float4 ta = t4[0], tb = t4[1], tc = t4[2];

        const float wv[4]  = {wq.x, wq.y, wq.z, wq.w};
        const float sv[12] = {sa.x, sa.y, sa.z, sa.w, sb.x, sb.y,
                              sb.z, sb.w, sc.x, sc.y, sc.z, sc.w};
        const float tv[12] = {ta.x, ta.y, ta.z, ta.w, tb.x, tb.y,
                              tb.z, tb.w, tc.x, tc.y, tc.z, tc.w};

#pragma unroll
        for (int k = 0; k < 4; ++k) {
            const float wvk = (wv[k] < 0.5f) ? 0.f : wv[k];
            const float sx = sv[3 * k + 0], sy = sv[3 * k + 1], sz = sv[3 * k + 2];
            const float tx = tv[3 * k + 0], ty = tv[3 * k + 1], tz = tv[3 * k + 2];
            const float wsx = wvk * sx, wsy = wvk * sy, wsz = wvk * sz;
            acc[0] += wvk;
            acc[1] += wsx; acc[2] += wsy; acc[3] += wsz;
            acc[4] += wvk * tx; acc[5] += wvk * ty; acc[6] += wvk * tz;
            acc[7]  += wsx * tx; acc[8]  += wsx * ty; acc[9]  += wsx * tz;
            acc[10] += wsy * tx; acc[11] += wsy * ty; acc[12] += wsy * tz;
            acc[13] += wsz * tx; acc[14] += wsz * ty; acc[15] += wsz * tz;
        }
    }

    // Transposed butterfly within each wave: 8+4+2+1 shuffles + 2 final levels.
    const int wave = tid >> 6;
    const int lane = tid & 63;
    bflevel<1, 8>(acc, lane);
    bflevel<2, 4>(acc, lane);
    bflevel<4, 2>(acc, lane);
    bflevel<8, 1>(acc, lane);
    acc[0] += __shfl_xor(acc[0], 16, 64);
    acc[0] += __shfl_xor(acc[0], 32, 64);

    // lane L (<16) holds wave-total for original index bitrev4(L).
    __shared__ float lds[4][16];
    __shared__ float s16f[16];
    if (lane < 16) {
        const int idx = ((lane & 1) << 3) | ((lane & 2) << 1) |
                        ((lane & 4) >> 1) | ((lane & 8) >> 3);
        lds[wave][idx] = acc[0];
    }
    __syncthreads();
    if (tid < 16)
        s16f[tid] = lds[0][tid] + lds[1][tid] + lds[2][tid] + lds[3][tid];
    __syncthreads();

    if (tid != 0) return;

    // ---------------- fp64 Kabsch epilogue (single thread) ----------------
    float s16[16];
#pragma unroll
    for (int i = 0; i < 16; ++i) s16[i] = s16f[i];

    const double Sw = (double)s16[0];
    const double D = Sw + 1e-5;
    const double invD = 1.0 / D;
    double sc[3], tc[3];
#pragma unroll
    for (int i = 0; i < 3; ++i) {
        sc[i] = (double)s16[1 + i] * invD;
        tc[i] = (double)s16[4 + i] * invD;
    }
    const double f = 2.0 - Sw * invD;

    double H[3][3];
#pragma unroll
    for (int d = 0; d < 3; ++d)
#pragma unroll
        for (int e = 0; e < 3; ++e)
            H[d][e] = (double)s16[7 + 3 * d + e] * invD - sc[d] * tc[e] * f;

    // A = H^T H (symmetric PSD)
    double A[3][3];
#pragma unroll
    for (int i = 0; i < 3; ++i)
#pragma unroll
        for (int j = 0; j < 3; ++j)
            A[i][j] = H[0][i] * H[0][j] + H[1][i] * H[1][j] + H[2][i] * H[2][j];

    double V[3][3] = {{1, 0, 0}, {0, 1, 0}, {0, 0, 1}};
#pragma unroll
    for (int sweep = 0; sweep < 8; ++sweep) {
        jrot<0, 1>(A, V);
        jrot<0, 2>(A, V);
        jrot<1, 2>(A, V);
    }

    // sort eigenvalues descending
    const double l0 = A[0][0], l1 = A[1][1], l2 = A[2][2];
    int i0 = 0; double lm = l0;
    if (l1 > lm) { lm = l1; i0 = 1; }
    if (l2 > lm) { lm = l2; i0 = 2; }
    int i2 = 0; double ls = l0;
    if (l1 < ls) { ls = l1; i2 = 1; }
    if (l2 < ls) { ls = l2; i2 = 2; }
    if (i2 == i0) i2 = (i0 + 1) % 3;
    const int i1 = 3 - i0 - i2;

    double v1[3], v2[3], v3[3];
#pragma unroll
    for (int k = 0; k < 3; ++k) {
        v1[k] = V[k][i0];
        v2[k] = V[k][i1];
        v3[k] = V[k][i2];
    }

    // u1 = normalize(H v1); u2 = normalize(H v2 orth. vs u1); u3 = u1 x u2
    double u1[3], u2[3], u3[3];
    matvec3(H, v1, u1);
    const double n1 = sqrt(dot3(u1, u1));
    const double inv1 = 1.0 / fmax(n1, 1e-300);
#pragma unroll
    for (int k = 0; k < 3; ++k) u1[k] *= inv1;

    matvec3(H, v2, u2);
    const double d12 = dot3(u2, u1);
#pragma unroll
    for (int k = 0; k < 3; ++k) u2[k] -= d12 * u1[k];
    double n2 = sqrt(dot3(u2, u2));
    if (n2 < 1e-14 * fmax(n1, 1e-300)) {
        // degenerate rank<=1: any vector orthogonal to u1
        double ax[3] = {1.0, 0.0, 0.0};
        if (fabs(u1[0]) > 0.9) { ax[0] = 0.0; ax[1] = 1.0; }
        cross3(u1, ax, u2);
        n2 = sqrt(dot3(u2, u2));
    }
    const double inv2 = 1.0 / fmax(n2, 1e-300);
#pragma unroll
    for (int k = 0; k < 3; ++k) u2[k] *= inv2;
    cross3(u1, u2, u3);

    // R = v1 u1^T + v2 u2^T + sign(det V) * v3 u3^T
    double cr[3];
    cross3(v2, v3, cr);
    const double detV = dot3(v1, cr);
    const double s3 = (detV < 0.0) ? -1.0 : 1.0;

    double R[3][3];
#pragma unroll
    for (int i = 0; i < 3; ++i)
#pragma unroll
        for (int j = 0; j < 3; ++j)
            R[i][j] = v1[i] * u1[j] + v2[i] * u2[j] + s3 * v3[i] * u3[j];

    double t[3];
#pragma unroll
    for (int i = 0; i < 3; ++i)
        t[i] = tc[i] - (R[i][0] * sc[0] + R[i][1] * sc[1] + R[i][2] * sc[2]);

    float* outR = out + (size_t)b * 9;
#pragma unroll
    for (int i = 0; i < 3; ++i)
#pragma unroll
        for (int j = 0; j < 3; ++j)
            outR[3 * i + j] = (float)R[i][j];
    float* outT = out + (size_t)B * 9 + (size_t)b * 3;
#pragma unroll
    for (int i = 0; i < 3; ++i) outT[i] = (float)t[i];
}

extern "C" void kernel_launch(void* const* d_in, const int* in_sizes, int n_in,
                              void* d_out, int out_size, void* d_ws, size_t ws_size,
                              hipStream_t stream)
{
    const float* src = (const float*)d_in[0];
    const float* tgt = (const float*)d_in[1];
    const float* w   = (const float*)d_in[2];
    float* out = (float*)d_out;
    const int B = in_sizes[2] / NPTS;  // 4096

    wp_fused_kernel<<<B, THREADS, 0, stream>>>(src, tgt, w, out, B);
}

// Round 5
// 45.496 us; speedup vs baseline: 1.4061x; 1.4061x over previous
//
#include <hip/hip_runtime.h>
#include <math.h>

#define NPTS 2048
#define THREADS 256

// ---------------- Kernel 1: per-batch weighted reduction ----------------
// Per batch b, 16 sums over n:
//   [0] w  [1..3] w*src  [4..6] w*tgt  [7..15] w*src_d*tgt_e (row-major)
// w thresholded (w<0.5 -> 0), UNNORMALIZED.
// Straight-line: each thread owns 8 points (two groups of 4), issues all
// 14 float4 loads up front (pinned by sched_barrier), then computes.

__device__ inline void acc4(const float4 wq, const float4 s0, const float4 s1,
                            const float4 s2, const float4 t0, const float4 t1,
                            const float4 t2, float acc[16])
{
    const float wv[4]  = {wq.x, wq.y, wq.z, wq.w};
    const float sv[12] = {s0.x, s0.y, s0.z, s0.w, s1.x, s1.y,
                          s1.z, s1.w, s2.x, s2.y, s2.z, s2.w};
    const float tv[12] = {t0.x, t0.y, t0.z, t0.w, t1.x, t1.y,
                          t1.z, t1.w, t2.x, t2.y, t2.z, t2.w};
#pragma unroll
    for (int k = 0; k < 4; ++k) {
        const float wvk = (wv[k] < 0.5f) ? 0.f : wv[k];
        const float sx = sv[3 * k + 0], sy = sv[3 * k + 1], sz = sv[3 * k + 2];
        const float tx = tv[3 * k + 0], ty = tv[3 * k + 1], tz = tv[3 * k + 2];
        const float wsx = wvk * sx, wsy = wvk * sy, wsz = wvk * sz;
        acc[0] += wvk;
        acc[1] += wsx; acc[2] += wsy; acc[3] += wsz;
        acc[4] += wvk * tx; acc[5] += wvk * ty; acc[6] += wvk * tz;
        acc[7]  += wsx * tx; acc[8]  += wsx * ty; acc[9]  += wsx * tz;
        acc[10] += wsy * tx; acc[11] += wsy * ty; acc[12] += wsy * tz;
        acc[13] += wsz * tx; acc[14] += wsz * ty; acc[15] += wsz * tz;
    }
}

// One transposed-butterfly level: halves the live accumulator count.
template <int M, int HALF>
__device__ inline void bflevel(float acc[16], int lane)
{
    const bool hi = lane & M;
#pragma unroll
    for (int j = 0; j < HALF; ++j) {
        const float keep = hi ? acc[j + HALF] : acc[j];
        const float send = hi ? acc[j] : acc[j + HALF];
        acc[j] = keep + __shfl_xor(send, M, 64);
    }
}

__global__ __launch_bounds__(THREADS, 4) void wp_reduce_kernel(
    const float* __restrict__ src, const float* __restrict__ tgt,
    const float* __restrict__ w, float* __restrict__ ws)
{
    const int b = blockIdx.x;
    const int tid = threadIdx.x;
    const float* sp = src + (size_t)b * NPTS * 3;
    const float* tp = tgt + (size_t)b * NPTS * 3;
    const float* wp = w + (size_t)b * NPTS;

    // group A: points [tid*4, tid*4+4); group B: +1024 points
    const int nA = tid * 4;
    const int nB = 1024 + tid * 4;

    // ---- issue all 14 loads ----
    const float4 wqA = *reinterpret_cast<const float4*>(wp + nA);
    const float4 wqB = *reinterpret_cast<const float4*>(wp + nB);
    const float4* sA = reinterpret_cast<const float4*>(sp + 3 * nA);
    const float4 sA0 = sA[0], sA1 = sA[1], sA2 = sA[2];
    const float4* sB = reinterpret_cast<const float4*>(sp + 3 * nB);
    const float4 sB0 = sB[0], sB1 = sB[1], sB2 = sB[2];
    const float4* tA = reinterpret_cast<const float4*>(tp + 3 * nA);
    const float4 tA0 = tA[0], tA1 = tA[1], tA2 = tA[2];
    const float4* tB = reinterpret_cast<const float4*>(tp + 3 * nB);
    const float4 tB0 = tB[0], tB1 = tB[1], tB2 = tB[2];
    __builtin_amdgcn_sched_barrier(0);   // keep all loads issued above compute

    float acc[16];
#pragma unroll
    for (int i = 0; i < 16; ++i) acc[i] = 0.f;

    acc4(wqA, sA0, sA1, sA2, tA0, tA1, tA2, acc);
    acc4(wqB, sB0, sB1, sB2, tB0, tB1, tB2, acc);

    // Transposed butterfly within each wave: 8+4+2+1 shuffles + 2 final levels.
    const int wave = tid >> 6;
    const int lane = tid & 63;
    bflevel<1, 8>(acc, lane);
    bflevel<2, 4>(acc, lane);
    bflevel<4, 2>(acc, lane);
    bflevel<8, 1>(acc, lane);
    acc[0] += __shfl_xor(acc[0], 16, 64);
    acc[0] += __shfl_xor(acc[0], 32, 64);

    // lane L (<16) holds wave-total for original index bitrev4(L).
    __shared__ float lds[4][16];
    if (lane < 16) {
        const int idx = ((lane & 1) << 3) | ((lane & 2) << 1) |
                        ((lane & 4) >> 1) | ((lane & 8) >> 3);
        lds[wave][idx] = acc[0];
    }
    __syncthreads();
    if (tid < 16) {
        const float v = lds[0][tid] + lds[1][tid] + lds[2][tid] + lds[3][tid];
        ws[(size_t)b * 16 + tid] = v;
    }
}

// ---------------- Kernel 2: per-batch 3x3 Kabsch (fp64 Jacobi SVD) ----------------

template <int P, int Q>
__device__ inline void jrot(double A[3][3], double V[3][3])
{
    const double apq = A[P][Q];
    if (fabs(apq) < 1e-300) return;
    const double theta = (A[Q][Q] - A[P][P]) / (2.0 * apq);
    const double t = ((theta >= 0.0) ? 1.0 : -1.0) /
                     (fabs(theta) + sqrt(theta * theta + 1.0));
    const double c = 1.0 / sqrt(t * t + 1.0);
    const double s = t * c;
#pragma unroll
    for (int k = 0; k < 3; ++k) {
        const double akp = A[k][P], akq = A[k][Q];
        A[k][P] = c * akp - s * akq;
        A[k][Q] = s * akp + c * akq;
    }
#pragma unroll
    for (int k = 0; k < 3; ++k) {
        const double apk = A[P][k], aqk = A[Q][k];
        A[P][k] = c * apk - s * aqk;
        A[Q][k] = s * apk + c * aqk;
    }
#pragma unroll
    for (int k = 0; k < 3; ++k) {
        const double vkp = V[k][P], vkq = V[k][Q];
        V[k][P] = c * vkp - s * vkq;
        V[k][Q] = s * vkp + c * vkq;
    }
}

__device__ inline void matvec3(const double H[3][3], const double v[3], double u[3])
{
#pragma unroll
    for (int i = 0; i < 3; ++i)
        u[i] = H[i][0] * v[0] + H[i][1] * v[1] + H[i][2] * v[2];
}

__device__ inline double dot3(const double a[3], const double b[3])
{
    return a[0] * b[0] + a[1] * b[1] + a[2] * b[2];
}

__device__ inline void cross3(const double a[3], const double b[3], double c[3])
{
    c[0] = a[1] * b[2] - a[2] * b[1];
    c[1] = a[2] * b[0] - a[0] * b[2];
    c[2] = a[0] * b[1] - a[1] * b[0];
}

__global__ void wp_svd_kernel(const float* __restrict__ ws, float* __restrict__ out,
                              int B)
{
    const int b = blockIdx.x * blockDim.x + threadIdx.x;
    if (b >= B) return;

    float s16[16];
#pragma unroll
    for (int i = 0; i < 16; ++i) s16[i] = ws[(size_t)b * 16 + i];

    const double Sw = (double)s16[0];
    const double D = Sw + 1e-5;
    const double invD = 1.0 / D;
    double sc[3], tc[3];
#pragma unroll
    for (int i = 0; i < 3; ++i) {
        sc[i] = (double)s16[1 + i] * invD;
        tc[i] = (double)s16[4 + i] * invD;
    }
    const double f = 2.0 - Sw * invD;

    double H[3][3];
#pragma unroll
    for (int d = 0; d < 3; ++d)
#pragma unroll
        for (int e = 0; e < 3; ++e)
            H[d][e] = (double)s16[7 + 3 * d + e] * invD - sc[d] * tc[e] * f;

    // A = H^T H (symmetric PSD)
    double A[3][3];
#pragma unroll
    for (int i = 0; i < 3; ++i)
#pragma unroll
        for (int j = 0; j < 3; ++j)
            A[i][j] = H[0][i] * H[0][j] + H[1][i] * H[1][j] + H[2][i] * H[2][j];

    double V[3][3] = {{1, 0, 0}, {0, 1, 0}, {0, 0, 1}};
#pragma unroll
    for (int sweep = 0; sweep < 5; ++sweep) {
        jrot<0, 1>(A, V);
        jrot<0, 2>(A, V);
        jrot<1, 2>(A, V);
    }

    // sort eigenvalues descending
    const double l0 = A[0][0], l1 = A[1][1], l2 = A[2][2];
    int i0 = 0; double lm = l0;
    if (l1 > lm) { lm = l1; i0 = 1; }
    if (l2 > lm) { lm = l2; i0 = 2; }
    int i2 = 0; double ls = l0;
    if (l1 < ls) { ls = l1; i2 = 1; }
    if (l2 < ls) { ls = l2; i2 = 2; }
    if (i2 == i0) i2 = (i0 + 1) % 3;
    const int i1 = 3 - i0 - i2;

    double v1[3], v2[3], v3[3];
#pragma unroll
    for (int k = 0; k < 3; ++k) {
        v1[k] = V[k][i0];
        v2[k] = V[k][i1];
        v3[k] = V[k][i2];
    }

    // u1 = normalize(H v1); u2 = normalize(H v2 orth. vs u1); u3 = u1 x u2
    double u1[3], u2[3], u3[3];
    matvec3(H, v1, u1);
    const double n1 = sqrt(dot3(u1, u1));
    const double inv1 = 1.0 / fmax(n1, 1e-300);
#pragma unroll
    for (int k = 0; k < 3; ++k) u1[k] *= inv1;

    matvec3(H, v2, u2);
    const double d12 = dot3(u2, u1);
#pragma unroll
    for (int k = 0; k < 3; ++k) u2[k] -= d12 * u1[k];
    double n2 = sqrt(dot3(u2, u2));
    if (n2 < 1e-14 * fmax(n1, 1e-300)) {
        // degenerate rank<=1: any vector orthogonal to u1
        double ax[3] = {1.0, 0.0, 0.0};
        if (fabs(u1[0]) > 0.9) { ax[0] = 0.0; ax[1] = 1.0; }
        cross3(u1, ax, u2);
        n2 = sqrt(dot3(u2, u2));
    }
    const double inv2 = 1.0 / fmax(n2, 1e-300);
#pragma unroll
    for (int k = 0; k < 3; ++k) u2[k] *= inv2;
    cross3(u1, u2, u3);

    // R = v1 u1^T + v2 u2^T + sign(det V) * v3 u3^T
    double cr[3];
    cross3(v2, v3, cr);
    const double detV = dot3(v1, cr);
    const double s3 = (detV < 0.0) ? -1.0 : 1.0;

    double R[3][3];
#pragma unroll
    for (int i = 0; i < 3; ++i)
#pragma unroll
        for (int j = 0; j < 3; ++j)
            R[i][j] = v1[i] * u1[j] + v2[i] * u2[j] + s3 * v3[i] * u3[j];

    double t[3];
#pragma unroll
    for (int i = 0; i < 3; ++i)
        t[i] = tc[i] - (R[i][0] * sc[0] + R[i][1] * sc[1] + R[i][2] * sc[2]);

    float* outR = out + (size_t)b * 9;
#pragma unroll
    for (int i = 0; i < 3; ++i)
#pragma unroll
        for (int j = 0; j < 3; ++j)
            outR[3 * i + j] = (float)R[i][j];
    float* outT = out + (size_t)B * 9 + (size_t)b * 3;
#pragma unroll
    for (int i = 0; i < 3; ++i) outT[i] = (float)t[i];
}

extern "C" void kernel_launch(void* const* d_in, const int* in_sizes, int n_in,
                              void* d_out, int out_size, void* d_ws, size_t ws_size,
                              hipStream_t stream)
{
    const float* src = (const float*)d_in[0];
    const float* tgt = (const float*)d_in[1];
    const float* w   = (const float*)d_in[2];
    float* out = (float*)d_out;
    float* ws  = (float*)d_ws;
    const int B = in_sizes[2] / NPTS;  // 4096

    wp_reduce_kernel<<<B, THREADS, 0, stream>>>(src, tgt, w, ws);
    wp_svd_kernel<<<(B + 63) / 64, 64, 0, stream>>>(ws, out, B);
}